// Round 8
// baseline (503.912 us; speedup 1.0000x reference)
//
#include <hip/hip_runtime.h>
#include <hip/hip_bf16.h>
#include <math.h>

// Problem shape (fixed): B=32, S=4096, D=1024, L=1
#define D_DIM 1024
#define S_DIM 4096
#define B_DIM 32
#define M_TOTAL (B_DIM * S_DIM)   // 131072 rows

#define KQ   128                  // K per pipeline phase
#define NPH  8                    // phases (8*128 = 1024)

using short8 = __attribute__((ext_vector_type(8))) short;
using f32x4  = __attribute__((ext_vector_type(4))) float;

// fp32 -> bf16, round-to-nearest-even (one-time weight conversion kernels)
static __device__ __forceinline__ unsigned short f2bf(float x) {
    unsigned int u = __float_as_uint(x);
    u += 0x7fffu + ((u >> 16) & 1u);
    return (unsigned short)(u >> 16);
}

// packed bf16 pair via HW v_cvt_pk_bf16_f32 (RNE) — same rounding as f2bf
static __device__ __forceinline__ unsigned int pk2(float lo, float hi) {
    __hip_bfloat162 h = __float22bfloat162_rn(float2{lo, hi});
    unsigned int u; __builtin_memcpy(&u, &h, 4); return u;
}

// tanh via exp2-backed __expf; ~1e-6 abs err (we need ~1e-3)
static __device__ __forceinline__ float fast_tanh(float x) {
    float e2 = __expf(2.0f * x);
    return 1.0f - 2.0f * __builtin_amdgcn_rcpf(e2 + 1.0f);
}

// ---------------------------------------------------------------------------
// Detect attn_mask dtype: int32 (0/1 -> high bytes of every word are 0)
// vs. bool/uint8 (random 0/1 bytes -> some high byte nonzero).
__global__ __launch_bounds__(256) void mask_detect_kernel(
        const unsigned int* __restrict__ m, int* __restrict__ flag) {
    __shared__ unsigned int red[4];
    int t = threadIdx.x;
    unsigned int acc = 0;
    for (int i = t; i < 32768; i += 256) acc |= (m[i] & 0xFFFFFF00u);
    #pragma unroll
    for (int k = 1; k <= 32; k <<= 1) acc |= __shfl_xor(acc, k, 64);
    if ((t & 63) == 0) red[t >> 6] = acc;
    __syncthreads();
    if (t == 0) flag[0] = ((red[0] | red[1] | red[2] | red[3]) != 0) ? 1 : 0;
}

// ---------------------------------------------------------------------------
// Convert Wa_w [1024][1024] fp32 -> bf16 in FRAGMENT-TILED layout:
//   Wt[((et*32 + kc)*64 + lane)*8 + j] = bf16( W[et*16 + (lane&15)]
//                                              [kc*32 + (lane>>4)*8 + j] )
// One wave's B-fragment load = one coalesced 1 KiB read.  (R4 verbatim)
__global__ __launch_bounds__(256) void wconv_kernel(
        const float* __restrict__ W, unsigned short* __restrict__ Wt) {
    int tid  = blockIdx.x * 256 + threadIdx.x;   // 0..131071, one short8 each
    int lane = tid & 63;
    int kc   = (tid >> 6) & 31;
    int et   = tid >> 11;
    int e = et * 16 + (lane & 15);
    int k = kc * 32 + (lane >> 4) * 8;
    const float* src = W + (size_t)e * D_DIM + k;
    float4 v0 = *(const float4*)(src);
    float4 v1 = *(const float4*)(src + 4);
    short8 pk;
    pk[0] = (short)f2bf(v0.x); pk[1] = (short)f2bf(v0.y);
    pk[2] = (short)f2bf(v0.z); pk[3] = (short)f2bf(v0.w);
    pk[4] = (short)f2bf(v1.x); pk[5] = (short)f2bf(v1.y);
    pk[6] = (short)f2bf(v1.z); pk[7] = (short)f2bf(v1.w);
    *(short8*)(Wt + (size_t)tid * 8) = pk;
}

// ---------------------------------------------------------------------------
// off[b][e] = sum_d h[0][b][d]*Ua_w[e][d] + Ua_b[e] + Wa_b[e]  (R4 verbatim)
__global__ __launch_bounds__(256) void off_kernel(
        const float* __restrict__ h, const float* __restrict__ Uw,
        const float* __restrict__ Ub, const float* __restrict__ Wab,
        float* __restrict__ off) {
    int wg   = blockIdx.x * 4 + (threadIdx.x >> 6);
    int lane = threadIdx.x & 63;
    int b = wg >> 10, e = wg & 1023;
    const float4* h4 = (const float4*)(h + (size_t)b * D_DIM);
    const float4* u4 = (const float4*)(Uw + (size_t)e * D_DIM);
    float s = 0.f;
    #pragma unroll
    for (int c = 0; c < 4; ++c) {
        float4 a = h4[c * 64 + lane];
        float4 w = u4[c * 64 + lane];
        s += a.x * w.x + a.y * w.y + a.z * w.z + a.w * w.w;
    }
    #pragma unroll
    for (int m = 32; m; m >>= 1) s += __shfl_xor(s, m, 64);
    if (lane == 0) off[b * D_DIM + e] = s + Ub[e] + Wab[e];
}

// ---------------------------------------------------------------------------
// Zero the score accumulation buffer (quarters atomicAdd into it).
__global__ __launch_bounds__(256) void zero_kernel(float* __restrict__ p) {
    ((float4*)p)[blockIdx.x * 256 + threadIdx.x] = (float4){0.f, 0.f, 0.f, 0.f};
}

// ---------------------------------------------------------------------------
// Fused partial scores, column-QUARTER blocks:
//   scores[row] += sum_{e in quarter} Va[e]*tanh((A@W^T)[row][e] + off[b][e])
//
// 4 waves (256 thr); block = 64 rows x 256 cols; wave tile 64x64.
// __launch_bounds__(256,3): 3 blocks/CU (12 waves, reg cap ~170) -> ~40 free
// VGPRs spent on B register double-buffering across kk-steps AND phases.
// Stage loads (HBM) are issued BETWEEN B-prefetch issues so every MFMA's B
// operand is OLDER in the in-order vmcnt queue than any pending stage load
// (no implicit drain). XCD-quad swizzle: 4 quarters of a row-panel on one
// XCD -> A served from L2/L3 after first quarter.
__global__ __launch_bounds__(256, 3) void score_kernel(
        const float* __restrict__ A,            // [M][1024] fp32
        const unsigned short* __restrict__ Wt,  // tiled bf16 (see wconv)
        const float* __restrict__ off,          // [32][1024]
        const float* __restrict__ Va,           // [1024]
        float* __restrict__ scores)             // [M] accumulated
{
    __shared__ short As[2][64 * KQ];    // 2 x 16 KiB, XOR-swizzled rows
    __shared__ float score_lds[64];

    // XCD-quad swizzle: grid 8192 = 8 XCDs x 1024; on one XCD, consecutive
    // blocks are the 4 column-quarters of one row-panel.
    const int bid  = blockIdx.x;
    const int pr   = (bid & 7) * 256 + (bid >> 5);          // row-tile 0..2047
    const int qr   = (bid >> 3) & 3;                        // column quarter
    const int row0 = pr * 64;
    const int b    = row0 >> 12;        // 4096 rows per batch

    const int t = threadIdx.x;
    if (t < 64) score_lds[t] = 0.f;

    const int wave = t >> 6, lane = t & 63;
    const int l15 = lane & 15, lhi = lane >> 4;
    const int e0 = qr * 256 + wave * 64;

    // coalesced B base: fragment (cf, kglob) at +(cf*32 + kglob)*512
    const unsigned short* WtB =
        Wt + ((size_t)(qr * 16 + wave * 4) * 32) * 512 + (size_t)lane * 8;

    // staging: thread covers row sr, 32 consecutive k-floats
    const int sr = t >> 2;              // row 0..63
    const int sk = (t & 3) * 32;        // float/short col base
    const float* Asrc = A + (size_t)(row0 + sr) * D_DIM + sk;
    const int swz = (sr & 7) << 3;
    const int sidx0 = sr * KQ + ((sk +  0) ^ swz);
    const int sidx1 = sr * KQ + ((sk +  8) ^ swz);
    const int sidx2 = sr * KQ + ((sk + 16) ^ swz);
    const int sidx3 = sr * KQ + ((sk + 24) ^ swz);

    f32x4 acc[4][4];
    #pragma unroll
    for (int rf = 0; rf < 4; ++rf)
        #pragma unroll
        for (int cf = 0; cf < 4; ++cf) acc[rf][cf] = (f32x4){0.f, 0.f, 0.f, 0.f};

    short8 B0[4], B1[4];

    // one kk-step: prefetch B(kg+1) into PRE, optional stage issue, MFMA(USE)
    #define MF(KK, USE, PRE, STAGE_CODE) do {                                 \
        const int kgn_ = (q * 4 + KK + 1 < 32) ? q * 4 + KK + 1 : 31;         \
        _Pragma("unroll")                                                     \
        for (int cf = 0; cf < 4; ++cf)                                        \
            PRE[cf] = *(const short8*)(WtB + (size_t)(cf * 32 + kgn_) * 512); \
        STAGE_CODE                                                            \
        short8 af[4];                                                         \
        const int k0_ = KK * 32 + lhi * 8;                                    \
        _Pragma("unroll")                                                     \
        for (int rf = 0; rf < 4; ++rf) {                                      \
            int row = rf * 16 + l15;                                          \
            af[rf] = *(const short8*)(&As[cur][row * KQ                       \
                       + (k0_ ^ ((row & 7) << 3))]);                          \
        }                                                                     \
        __builtin_amdgcn_s_setprio(1);                                        \
        _Pragma("unroll")                                                     \
        for (int rf = 0; rf < 4; ++rf)                                        \
            _Pragma("unroll")                                                 \
            for (int cf = 0; cf < 4; ++cf)                                    \
                acc[rf][cf] = __builtin_amdgcn_mfma_f32_16x16x32_bf16(        \
                    af[rf], USE[cf], acc[rf][cf], 0, 0, 0);                   \
        __builtin_amdgcn_s_setprio(0);                                        \
    } while (0)

    // ---- prologue: stage panel 0 (serial, once) + first B fragments ----
    {
        float4 v0 = *(const float4*)(Asrc +  0);
        float4 v1 = *(const float4*)(Asrc +  4);
        float4 v2 = *(const float4*)(Asrc +  8);
        float4 v3 = *(const float4*)(Asrc + 12);
        float4 v4 = *(const float4*)(Asrc + 16);
        float4 v5 = *(const float4*)(Asrc + 20);
        float4 v6 = *(const float4*)(Asrc + 24);
        float4 v7 = *(const float4*)(Asrc + 28);
        uint4 o;
        o.x = pk2(v0.x, v0.y); o.y = pk2(v0.z, v0.w);
        o.z = pk2(v1.x, v1.y); o.w = pk2(v1.z, v1.w);
        *(uint4*)(&As[0][sidx0]) = o;
        o.x = pk2(v2.x, v2.y); o.y = pk2(v2.z, v2.w);
        o.z = pk2(v3.x, v3.y); o.w = pk2(v3.z, v3.w);
        *(uint4*)(&As[0][sidx1]) = o;
        o.x = pk2(v4.x, v4.y); o.y = pk2(v4.z, v4.w);
        o.z = pk2(v5.x, v5.y); o.w = pk2(v5.z, v5.w);
        *(uint4*)(&As[0][sidx2]) = o;
        o.x = pk2(v6.x, v6.y); o.y = pk2(v6.z, v6.w);
        o.z = pk2(v7.x, v7.y); o.w = pk2(v7.z, v7.w);
        *(uint4*)(&As[0][sidx3]) = o;
    }
    #pragma unroll
    for (int cf = 0; cf < 4; ++cf)
        B0[cf] = *(const short8*)(WtB + (size_t)(cf * 32 + 0) * 512);
    __syncthreads();

    for (int q = 0; q < NPH; ++q) {
        const int cur = q & 1;
        float4 p0, p1, p2, p3, p4, p5, p6, p7;

        MF(0, B0, B1, );
        MF(1, B1, B0,
           if (q < NPH - 1) {
               const float* nx = Asrc + (q + 1) * KQ;
               p0 = *(const float4*)(nx +  0);
               p1 = *(const float4*)(nx +  4);
               p2 = *(const float4*)(nx +  8);
               p3 = *(const float4*)(nx + 12);
           });
        MF(2, B0, B1,
           if (q < NPH - 1) {
               const float* nx = Asrc + (q + 1) * KQ;
               p4 = *(const float4*)(nx + 16);
               p5 = *(const float4*)(nx + 20);
               p6 = *(const float4*)(nx + 24);
               p7 = *(const float4*)(nx + 28);
           });
        MF(3, B1, B0, );    // prefetches next phase's kg0 into B0

        if (q < NPH - 1) {
            uint4 o;
            o.x = pk2(p0.x, p0.y); o.y = pk2(p0.z, p0.w);
            o.z = pk2(p1.x, p1.y); o.w = pk2(p1.z, p1.w);
            *(uint4*)(&As[cur ^ 1][sidx0]) = o;
            o.x = pk2(p2.x, p2.y); o.y = pk2(p2.z, p2.w);
            o.z = pk2(p3.x, p3.y); o.w = pk2(p3.z, p3.w);
            *(uint4*)(&As[cur ^ 1][sidx1]) = o;
            o.x = pk2(p4.x, p4.y); o.y = pk2(p4.z, p4.w);
            o.z = pk2(p5.x, p5.y); o.w = pk2(p5.z, p5.w);
            *(uint4*)(&As[cur ^ 1][sidx2]) = o;
            o.x = pk2(p6.x, p6.y); o.y = pk2(p6.z, p6.w);
            o.z = pk2(p7.x, p7.y); o.w = pk2(p7.z, p7.w);
            *(uint4*)(&As[cur ^ 1][sidx3]) = o;
        }
        __syncthreads();
    }

    // ---- epilogue: tanh + Va-weighted reduction over this wave's 64 cols ----
    // C/D layout (m89-verified): col = lane&15, row = (lane>>4)*4 + reg
    float sp[4][4];
    #pragma unroll
    for (int rf = 0; rf < 4; ++rf)
        #pragma unroll
        for (int j = 0; j < 4; ++j) sp[rf][j] = 0.f;

    #pragma unroll
    for (int cf = 0; cf < 4; ++cf) {
        int e = e0 + cf * 16 + l15;
        float offv = off[b * D_DIM + e];
        float vav  = Va[e];
        #pragma unroll
        for (int rf = 0; rf < 4; ++rf)
            #pragma unroll
            for (int j = 0; j < 4; ++j) {
                float x = acc[rf][cf][j] + offv;
                sp[rf][j] += fast_tanh(x) * vav;
            }
    }

    #pragma unroll
    for (int rf = 0; rf < 4; ++rf)
        #pragma unroll
        for (int j = 0; j < 4; ++j) {
            float v = sp[rf][j];
            v += __shfl_xor(v, 1, 64);
            v += __shfl_xor(v, 2, 64);
            v += __shfl_xor(v, 4, 64);
            v += __shfl_xor(v, 8, 64);
            if (l15 == 0) atomicAdd(&score_lds[rf * 16 + lhi * 4 + j], v);
        }
    __syncthreads();

    if (t < 64) atomicAdd(&scores[row0 + t], score_lds[t]);
}

// ---------------------------------------------------------------------------
// Masked softmax over S=4096 per batch row. One block per b.
__global__ __launch_bounds__(256) void softmax_kernel(
        const float* __restrict__ scores, const void* __restrict__ mask,
        const int* __restrict__ flag, float* __restrict__ out) {
    __shared__ float red[4];
    const int b = blockIdx.x, t = threadIdx.x;
    const float* s = scores + (size_t)b * S_DIM;
    const int mode8 = flag[0];

    float v[16];
    float mx = -INFINITY;
    if (mode8) {
        const unsigned char* m = (const unsigned char*)mask + (size_t)b * S_DIM;
        #pragma unroll
        for (int i = 0; i < 16; ++i) {
            int idx = i * 256 + t;
            v[i] = m[idx] ? s[idx] : -INFINITY;
            mx = fmaxf(mx, v[i]);
        }
    } else {
        const int* m = (const int*)mask + (size_t)b * S_DIM;
        #pragma unroll
        for (int i = 0; i < 16; ++i) {
            int idx = i * 256 + t;
            v[i] = m[idx] ? s[idx] : -INFINITY;
            mx = fmaxf(mx, v[i]);
        }
    }
    #pragma unroll
    for (int k = 1; k <= 32; k <<= 1) mx = fmaxf(mx, __shfl_xor(mx, k, 64));
    if ((t & 63) == 0) red[t >> 6] = mx;
    __syncthreads();
    mx = fmaxf(fmaxf(red[0], red[1]), fmaxf(red[2], red[3]));
    __syncthreads();

    float sum = 0.f;
    #pragma unroll
    for (int i = 0; i < 16; ++i) {
        v[i] = __expf(v[i] - mx);     // exp(-inf)=0 for masked slots
        sum += v[i];
    }
    #pragma unroll
    for (int k = 1; k <= 32; k <<= 1) sum += __shfl_xor(sum, k, 64);
    if ((t & 63) == 0) red[t >> 6] = sum;
    __syncthreads();
    sum = red[0] + red[1] + red[2] + red[3];
    float inv = 1.f / sum;
    #pragma unroll
    for (int i = 0; i < 16; ++i) out[(size_t)b * S_DIM + i * 256 + t] = v[i] * inv;
}

// ---------------------------------------------------------------------------
extern "C" void kernel_launch(void* const* d_in, const int* in_sizes, int n_in,
                              void* d_out, int out_size, void* d_ws, size_t ws_size,
                              hipStream_t stream) {
    const float* enc  = (const float*)d_in[0];   // [32][4096][1024]
    const float* dech = (const float*)d_in[1];   // [1][32][1024]
    const void*  mask = d_in[2];                 // [32][4096] bool-or-int32
    const float* Wa_w = (const float*)d_in[3];   // [1024][1024]
    const float* Wa_b = (const float*)d_in[4];   // [1024]
    const float* Ua_w = (const float*)d_in[5];   // [1024][1024]
    const float* Ua_b = (const float*)d_in[6];   // [1024]
    const float* Va_w = (const float*)d_in[7];   // [1][1024]
    // d_in[8] = Va_b: constant shift -> cancels in softmax.
    float* out = (float*)d_out;

    char* ws = (char*)d_ws;
    unsigned short* Wt = (unsigned short*)ws;                       // 2 MiB tiled
    float* off    = (float*)(ws + (1u << 21));                      // 128 KiB
    float* scores = (float*)(ws + (1u << 21) + (1u << 17));         // 512 KiB
    int*   flag   = (int*)(ws + (1u << 21) + (1u << 17) + (1u << 19));

    hipLaunchKernelGGL(mask_detect_kernel, dim3(1), dim3(256), 0, stream,
                       (const unsigned int*)mask, flag);
    hipLaunchKernelGGL(wconv_kernel, dim3(512), dim3(256), 0, stream, Wa_w, Wt);
    hipLaunchKernelGGL(off_kernel, dim3(8192), dim3(256), 0, stream,
                       dech, Ua_w, Ua_b, Wa_b, off);
    hipLaunchKernelGGL(zero_kernel, dim3(128), dim3(256), 0, stream, scores);
    hipLaunchKernelGGL(score_kernel, dim3(8192), dim3(256), 0, stream,
                       enc, Wt, off, Va_w, scores);
    hipLaunchKernelGGL(softmax_kernel, dim3(B_DIM), dim3(256), 0, stream,
                       scores, mask, flag, out);
}

// Round 9
// 416.676 us; speedup vs baseline: 1.2094x; 1.2094x over previous
//
#include <hip/hip_runtime.h>
#include <hip/hip_bf16.h>
#include <math.h>

// Problem shape (fixed): B=32, S=4096, D=1024, L=1
#define D_DIM 1024
#define S_DIM 4096
#define B_DIM 32
#define M_TOTAL (B_DIM * S_DIM)   // 131072 rows

#define KQ   128                  // K per pipeline phase
#define NPH  8                    // phases (8*128 = 1024)

using short8 = __attribute__((ext_vector_type(8))) short;
using f32x4  = __attribute__((ext_vector_type(4))) float;

// fp32 -> bf16, round-to-nearest-even (one-time weight conversion kernels)
static __device__ __forceinline__ unsigned short f2bf(float x) {
    unsigned int u = __float_as_uint(x);
    u += 0x7fffu + ((u >> 16) & 1u);
    return (unsigned short)(u >> 16);
}

// packed bf16 pair via HW v_cvt_pk_bf16_f32 (RNE) — same rounding as f2bf
static __device__ __forceinline__ unsigned int pk2(float lo, float hi) {
    __hip_bfloat162 h = __float22bfloat162_rn(float2{lo, hi});
    unsigned int u; __builtin_memcpy(&u, &h, 4); return u;
}

// tanh via exp2-backed __expf; ~1e-6 abs err (we need ~1e-3)
static __device__ __forceinline__ float fast_tanh(float x) {
    float e2 = __expf(2.0f * x);
    return 1.0f - 2.0f * __builtin_amdgcn_rcpf(e2 + 1.0f);
}

// ---------------------------------------------------------------------------
// Detect attn_mask dtype: int32 (0/1 -> high bytes of every word are 0)
// vs. bool/uint8 (random 0/1 bytes -> some high byte nonzero).
__global__ __launch_bounds__(256) void mask_detect_kernel(
        const unsigned int* __restrict__ m, int* __restrict__ flag) {
    __shared__ unsigned int red[4];
    int t = threadIdx.x;
    unsigned int acc = 0;
    for (int i = t; i < 32768; i += 256) acc |= (m[i] & 0xFFFFFF00u);
    #pragma unroll
    for (int k = 1; k <= 32; k <<= 1) acc |= __shfl_xor(acc, k, 64);
    if ((t & 63) == 0) red[t >> 6] = acc;
    __syncthreads();
    if (t == 0) flag[0] = ((red[0] | red[1] | red[2] | red[3]) != 0) ? 1 : 0;
}

// ---------------------------------------------------------------------------
// Convert Wa_w [1024][1024] fp32 -> bf16 in FRAGMENT-TILED layout:
//   Wt[((et*32 + kc)*64 + lane)*8 + j] = bf16( W[et*16 + (lane&15)]
//                                              [kc*32 + (lane>>4)*8 + j] )
// One wave's B-fragment load = one coalesced 1 KiB read.  (R7 verbatim)
__global__ __launch_bounds__(256) void wconv_kernel(
        const float* __restrict__ W, unsigned short* __restrict__ Wt) {
    int tid  = blockIdx.x * 256 + threadIdx.x;   // 0..131071, one short8 each
    int lane = tid & 63;
    int kc   = (tid >> 6) & 31;
    int et   = tid >> 11;
    int e = et * 16 + (lane & 15);
    int k = kc * 32 + (lane >> 4) * 8;
    const float* src = W + (size_t)e * D_DIM + k;
    float4 v0 = *(const float4*)(src);
    float4 v1 = *(const float4*)(src + 4);
    short8 pk;
    pk[0] = (short)f2bf(v0.x); pk[1] = (short)f2bf(v0.y);
    pk[2] = (short)f2bf(v0.z); pk[3] = (short)f2bf(v0.w);
    pk[4] = (short)f2bf(v1.x); pk[5] = (short)f2bf(v1.y);
    pk[6] = (short)f2bf(v1.z); pk[7] = (short)f2bf(v1.w);
    *(short8*)(Wt + (size_t)tid * 8) = pk;
}

// ---------------------------------------------------------------------------
// off[b][e] = sum_d h[0][b][d]*Ua_w[e][d] + Ua_b[e] + Wa_b[e]  (R4 verbatim)
__global__ __launch_bounds__(256) void off_kernel(
        const float* __restrict__ h, const float* __restrict__ Uw,
        const float* __restrict__ Ub, const float* __restrict__ Wab,
        float* __restrict__ off) {
    int wg   = blockIdx.x * 4 + (threadIdx.x >> 6);
    int lane = threadIdx.x & 63;
    int b = wg >> 10, e = wg & 1023;
    const float4* h4 = (const float4*)(h + (size_t)b * D_DIM);
    const float4* u4 = (const float4*)(Uw + (size_t)e * D_DIM);
    float s = 0.f;
    #pragma unroll
    for (int c = 0; c < 4; ++c) {
        float4 a = h4[c * 64 + lane];
        float4 w = u4[c * 64 + lane];
        s += a.x * w.x + a.y * w.y + a.z * w.z + a.w * w.w;
    }
    #pragma unroll
    for (int m = 32; m; m >>= 1) s += __shfl_xor(s, m, 64);
    if (lane == 0) off[b * D_DIM + e] = s + Ub[e] + Wab[e];
}

// ---------------------------------------------------------------------------
// Zero the score accumulation buffer (quarters atomicAdd into it).
__global__ __launch_bounds__(256) void zero_kernel(float* __restrict__ p) {
    ((float4*)p)[blockIdx.x * 256 + threadIdx.x] = (float4){0.f, 0.f, 0.f, 0.f};
}

// ---------------------------------------------------------------------------
// Fused partial scores, column-QUARTER blocks:
//   scores[row] += sum_{e in quarter} Va[e]*tanh((A@W^T)[row][e] + off[b][e])
//
// 8 waves (512 thr); block = 64 rows x 256 cols; wave tile 64x32 (acc=32
// regs) -> ~36 spare VGPRs fund a 4-deep named B register rotation (B0..B3,
// set index = kg&3, prefetch distance 2 kk-steps ~300cy > L2 latency).
// Queue discipline per phase:
//   [kk0: pre B(kg+2)][kk1: pre B(kg+3)][stage p0..p3][kk2: pre B'][kk3: pre B']
//   [cvt: vmcnt retires stage only; next-phase B' stays in flight][barrier]
// No B consumption waits behind a stage load; no stage wait drains B'.
// 2 blocks/CU (launch_bounds(512,4), reg class 128). XCD-quad swizzle: the
// 4 column-quarters of a row-panel sit consecutively on one XCD (A L2 reuse).
__global__ __launch_bounds__(512, 4) void score_kernel(
        const float* __restrict__ A,            // [M][1024] fp32
        const unsigned short* __restrict__ Wt,  // tiled bf16 (see wconv)
        const float* __restrict__ off,          // [32][1024]
        const float* __restrict__ Va,           // [1024]
        float* __restrict__ scores)             // [M] accumulated
{
    __shared__ short As[2][64 * KQ];    // 2 x 16 KiB, XOR-swizzled rows
    __shared__ float score_lds[64];

    // XCD-quad swizzle: grid 8192 = 8 XCDs x 1024; on one XCD, consecutive
    // blocks are the 4 column-quarters of one row-panel.
    const int bid  = blockIdx.x;
    const int pr   = (bid & 7) * 256 + (bid >> 5);          // row-tile 0..2047
    const int qr   = (bid >> 3) & 3;                        // column quarter
    const int row0 = pr * 64;
    const int b    = row0 >> 12;        // 4096 rows per batch

    const int t = threadIdx.x;
    if (t < 64) score_lds[t] = 0.f;

    const int wave = t >> 6, lane = t & 63;
    const int l15 = lane & 15, lhi = lane >> 4;
    const int e0 = qr * 256 + wave * 32;
    const int c0 = qr * 16 + wave * 2;  // 16-col tile base

    // B base: fragment (cf, kg) at WtB + cf*16384 + kg*512 (shorts)
    const unsigned short* WtB =
        Wt + (size_t)c0 * 32 * 512 + (size_t)lane * 8;

    // staging: thread covers row sr, 16 k-values (4 float4 -> 2 x 16B stores)
    const int sr = t >> 3;              // row 0..63
    const int sk = (t & 7) * 16;        // k-base 0..112
    const float* Asrc = A + (size_t)(row0 + sr) * D_DIM + sk;
    const int swz   = (sr & 7) << 3;
    const int sidx0 = sr * KQ + (sk ^ swz);
    const int sidx1 = sr * KQ + ((sk + 8) ^ swz);

    f32x4 acc[4][2];
    #pragma unroll
    for (int rf = 0; rf < 4; ++rf)
        #pragma unroll
        for (int cf = 0; cf < 2; ++cf) acc[rf][cf] = (f32x4){0.f, 0.f, 0.f, 0.f};

    short8 B0[2], B1[2], B2[2], B3[2];  // named 4-deep rotation (rule #20)

    #define LOADB(SET, KG) do {                                              \
        const int kg_ = (KG) < 31 ? (KG) : 31;                               \
        SET[0] = *(const short8*)(WtB + (size_t)kg_ * 512);                  \
        SET[1] = *(const short8*)(WtB + 16384 + (size_t)kg_ * 512);          \
    } while (0)

    // one kk-step: prefetch B(kg+2) into PRE, MFMA with USE (A from LDS)
    #define MF(KK, USE, PRE) do {                                            \
        LOADB(PRE, q * 4 + (KK) + 2);                                        \
        short8 af[4];                                                        \
        const int k0_ = (KK) * 32 + lhi * 8;                                 \
        _Pragma("unroll")                                                    \
        for (int rf = 0; rf < 4; ++rf) {                                     \
            int row = rf * 16 + l15;                                         \
            af[rf] = *(const short8*)(&As[cur][row * KQ                      \
                       + (k0_ ^ ((row & 7) << 3))]);                         \
        }                                                                    \
        __builtin_amdgcn_s_setprio(1);                                       \
        _Pragma("unroll")                                                    \
        for (int rf = 0; rf < 4; ++rf)                                       \
            _Pragma("unroll")                                                \
            for (int cf = 0; cf < 2; ++cf)                                   \
                acc[rf][cf] = __builtin_amdgcn_mfma_f32_16x16x32_bf16(       \
                    af[rf], USE[cf], acc[rf][cf], 0, 0, 0);                  \
        __builtin_amdgcn_s_setprio(0);                                       \
    } while (0)

    // ---- prologue: stage panel 0 + B(kg0), B(kg1) ----
    {
        float4 v0 = *(const float4*)(Asrc + 0);
        float4 v1 = *(const float4*)(Asrc + 4);
        float4 v2 = *(const float4*)(Asrc + 8);
        float4 v3 = *(const float4*)(Asrc + 12);
        uint4 o0, o1;
        o0.x = pk2(v0.x, v0.y); o0.y = pk2(v0.z, v0.w);
        o0.z = pk2(v1.x, v1.y); o0.w = pk2(v1.z, v1.w);
        o1.x = pk2(v2.x, v2.y); o1.y = pk2(v2.z, v2.w);
        o1.z = pk2(v3.x, v3.y); o1.w = pk2(v3.z, v3.w);
        *(uint4*)(&As[0][sidx0]) = o0;
        *(uint4*)(&As[0][sidx1]) = o1;
    }
    LOADB(B0, 0);
    LOADB(B1, 1);
    __syncthreads();

    for (int q = 0; q < NPH; ++q) {
        const int cur = q & 1;
        float4 p0, p1, p2, p3;

        MF(0, B0, B2);                  // pre kg+2 (this phase kk2)
        MF(1, B1, B3);                  // pre kg+3 (this phase kk3)

        // T14 issue: stage loads AFTER this phase's own B prefetches
        if (q < NPH - 1) {
            const float* nx = Asrc + (q + 1) * KQ;
            p0 = *(const float4*)(nx + 0);
            p1 = *(const float4*)(nx + 4);
            p2 = *(const float4*)(nx + 8);
            p3 = *(const float4*)(nx + 12);
        }

        MF(2, B2, B0);                  // pre kg+4 = next phase kk0
        MF(3, B3, B1);                  // pre kg+5 = next phase kk1

        // write-late: vmcnt here retires stage loads only (B0/B1 for the
        // next phase were issued after them and stay in flight)
        if (q < NPH - 1) {
            uint4 o0, o1;
            o0.x = pk2(p0.x, p0.y); o0.y = pk2(p0.z, p0.w);
            o0.z = pk2(p1.x, p1.y); o0.w = pk2(p1.z, p1.w);
            o1.x = pk2(p2.x, p2.y); o1.y = pk2(p2.z, p2.w);
            o1.z = pk2(p3.x, p3.y); o1.w = pk2(p3.z, p3.w);
            *(uint4*)(&As[cur ^ 1][sidx0]) = o0;
            *(uint4*)(&As[cur ^ 1][sidx1]) = o1;
        }
        __syncthreads();
    }

    // ---- epilogue: tanh + Va-weighted reduction over this wave's 32 cols ----
    // C/D layout (m89-verified): col = lane&15, row = (lane>>4)*4 + reg
    float sp[4][4];
    #pragma unroll
    for (int rf = 0; rf < 4; ++rf)
        #pragma unroll
        for (int j = 0; j < 4; ++j) sp[rf][j] = 0.f;

    #pragma unroll
    for (int cf = 0; cf < 2; ++cf) {
        int e = e0 + cf * 16 + l15;
        float offv = off[b * D_DIM + e];
        float vav  = Va[e];
        #pragma unroll
        for (int rf = 0; rf < 4; ++rf)
            #pragma unroll
            for (int j = 0; j < 4; ++j) {
                float x = acc[rf][cf][j] + offv;
                sp[rf][j] += fast_tanh(x) * vav;
            }
    }

    #pragma unroll
    for (int rf = 0; rf < 4; ++rf)
        #pragma unroll
        for (int j = 0; j < 4; ++j) {
            float v = sp[rf][j];
            v += __shfl_xor(v, 1, 64);
            v += __shfl_xor(v, 2, 64);
            v += __shfl_xor(v, 4, 64);
            v += __shfl_xor(v, 8, 64);
            if (l15 == 0) atomicAdd(&score_lds[rf * 16 + lhi * 4 + j], v);
        }
    __syncthreads();

    if (t < 64) atomicAdd(&scores[row0 + t], score_lds[t]);
}

// ---------------------------------------------------------------------------
// Masked softmax over S=4096 per batch row. One block per b.
__global__ __launch_bounds__(256) void softmax_kernel(
        const float* __restrict__ scores, const void* __restrict__ mask,
        const int* __restrict__ flag, float* __restrict__ out) {
    __shared__ float red[4];
    const int b = blockIdx.x, t = threadIdx.x;
    const float* s = scores + (size_t)b * S_DIM;
    const int mode8 = flag[0];

    float v[16];
    float mx = -INFINITY;
    if (mode8) {
        const unsigned char* m = (const unsigned char*)mask + (size_t)b * S_DIM;
        #pragma unroll
        for (int i = 0; i < 16; ++i) {
            int idx = i * 256 + t;
            v[i] = m[idx] ? s[idx] : -INFINITY;
            mx = fmaxf(mx, v[i]);
        }
    } else {
        const int* m = (const int*)mask + (size_t)b * S_DIM;
        #pragma unroll
        for (int i = 0; i < 16; ++i) {
            int idx = i * 256 + t;
            v[i] = m[idx] ? s[idx] : -INFINITY;
            mx = fmaxf(mx, v[i]);
        }
    }
    #pragma unroll
    for (int k = 1; k <= 32; k <<= 1) mx = fmaxf(mx, __shfl_xor(mx, k, 64));
    if ((t & 63) == 0) red[t >> 6] = mx;
    __syncthreads();
    mx = fmaxf(fmaxf(red[0], red[1]), fmaxf(red[2], red[3]));
    __syncthreads();

    float sum = 0.f;
    #pragma unroll
    for (int i = 0; i < 16; ++i) {
        v[i] = __expf(v[i] - mx);     // exp(-inf)=0 for masked slots
        sum += v[i];
    }
    #pragma unroll
    for (int k = 1; k <= 32; k <<= 1) sum += __shfl_xor(sum, k, 64);
    if ((t & 63) == 0) red[t >> 6] = sum;
    __syncthreads();
    sum = red[0] + red[1] + red[2] + red[3];
    float inv = 1.f / sum;
    #pragma unroll
    for (int i = 0; i < 16; ++i) out[(size_t)b * S_DIM + i * 256 + t] = v[i] * inv;
}

// ---------------------------------------------------------------------------
extern "C" void kernel_launch(void* const* d_in, const int* in_sizes, int n_in,
                              void* d_out, int out_size, void* d_ws, size_t ws_size,
                              hipStream_t stream) {
    const float* enc  = (const float*)d_in[0];   // [32][4096][1024]
    const float* dech = (const float*)d_in[1];   // [1][32][1024]
    const void*  mask = d_in[2];                 // [32][4096] bool-or-int32
    const float* Wa_w = (const float*)d_in[3];   // [1024][1024]
    const float* Wa_b = (const float*)d_in[4];   // [1024]
    const float* Ua_w = (const float*)d_in[5];   // [1024][1024]
    const float* Ua_b = (const float*)d_in[6];   // [1024]
    const float* Va_w = (const float*)d_in[7];   // [1][1024]
    // d_in[8] = Va_b: constant shift -> cancels in softmax.
    float* out = (float*)d_out;

    char* ws = (char*)d_ws;
    unsigned short* Wt = (unsigned short*)ws;                       // 2 MiB tiled
    float* off    = (float*)(ws + (1u << 21));                      // 128 KiB
    float* scores = (float*)(ws + (1u << 21) + (1u << 17));         // 512 KiB
    int*   flag   = (int*)(ws + (1u << 21) + (1u << 17) + (1u << 19));

    hipLaunchKernelGGL(mask_detect_kernel, dim3(1), dim3(256), 0, stream,
                       (const unsigned int*)mask, flag);
    hipLaunchKernelGGL(wconv_kernel, dim3(512), dim3(256), 0, stream, Wa_w, Wt);
    hipLaunchKernelGGL(off_kernel, dim3(8192), dim3(256), 0, stream,
                       dech, Ua_w, Ua_b, Wa_b, off);
    hipLaunchKernelGGL(zero_kernel, dim3(128), dim3(256), 0, stream, scores);
    hipLaunchKernelGGL(score_kernel, dim3(8192), dim3(512), 0, stream,
                       enc, Wt, off, Va_w, scores);
    hipLaunchKernelGGL(softmax_kernel, dim3(B_DIM), dim3(256), 0, stream,
                       scores, mask, flag, out);
}